// Round 5
// baseline (111.518 us; speedup 1.0000x reference)
//
#include <hip/hip_runtime.h>
#include <math.h>

#define C_WAY 10
#define K_SHOT 5
#define T_LEN 16
#define D_DIM 1024
#define NW 3
#define SEG_L 8

typedef __attribute__((ext_vector_type(8))) __bf16 bf16x8;
typedef __attribute__((ext_vector_type(4))) float f32x4;

static inline int cdiv(int a, int b) { return (a + b - 1) / b; }

__device__ __forceinline__ unsigned short f2bf(float f) {
    unsigned int u = __float_as_uint(f);
    u += 0x7fffu + ((u >> 16) & 1u);
    return (unsigned short)(u >> 16);
}
__device__ __forceinline__ float bf2f(unsigned short b) {
    return __uint_as_float(((unsigned int)b) << 16);
}
__device__ __forceinline__ ushort4 f2bf4(float4 v) {
    ushort4 b = {f2bf(v.x), f2bf(v.y), f2bf(v.z), f2bf(v.w)};
    return b;
}

__device__ __forceinline__ float wsum(float v) {
#pragma unroll
    for (int o = 32; o; o >>= 1) v += __shfl_xor(v, o);
    return v;
}
__device__ __forceinline__ float wmax(float v) {
#pragma unroll
    for (int o = 32; o; o >>= 1) v = fmaxf(v, __shfl_xor(v, o));
    return v;
}
__device__ __forceinline__ float wsum8(float v) {
#pragma unroll
    for (int o = 4; o; o >>= 1) v += __shfl_xor(v, o);
    return v;
}
__device__ __forceinline__ float wmax8(float v) {
#pragma unroll
    for (int o = 4; o; o >>= 1) v = fmaxf(v, __shfl_xor(v, o));
    return v;
}

// row-index maps (inline arithmetic)
__device__ __forceinline__ int cls_row(int i) {  // i in [0, 1200)
    int c = i / 120, rem = i - c * 120;
    int w = rem / 40, tok = rem - w * 40;
    return c * 80 + (tok >> 3) * 16 + w * 4 + (tok & 7);
}
__device__ __forceinline__ int qseg_row(int m) {  // m in [0, Q*24)
    int q = m / 24, rem = m - q * 24;
    return q * 16 + (rem >> 3) * 4 + (rem & 7);
}

// ================= fused prep =================
__global__ __launch_bounds__(256) void k_prep(const float* __restrict__ sup,
                                              const float* __restrict__ query,
                                              unsigned short* __restrict__ qbf,
                                              float* __restrict__ qrow_inv,
                                              unsigned short* __restrict__ qcondbf,
                                              unsigned short* __restrict__ supbf,
                                              unsigned short* __restrict__ protobf,
                                              float* __restrict__ pn_inv,
                                              unsigned short* __restrict__ scondbf,
                                              int Q) {
    __shared__ float red[NW][4];
    int b = blockIdx.x;
    int t = threadIdx.x, wv = t >> 6, lane = t & 63;
    if (b < Q) {
        int qq = b;
#pragma unroll
        for (int r0 = 0; r0 < 4; ++r0) {
            int row = qq * T_LEN + wv * 4 + r0;
            float sq = 0.f;
#pragma unroll
            for (int i = 0; i < 4; ++i) {
                float4 v = *(const float4*)&query[(size_t)row * D_DIM + (i * 64 + lane) * 4];
                *(ushort4*)&qbf[(size_t)row * D_DIM + (i * 64 + lane) * 4] = f2bf4(v);
                sq += v.x * v.x + v.y * v.y + v.z * v.z + v.w * v.w;
            }
            sq = wsum(sq);
            if (lane == 0) qrow_inv[row] = 1.0f / fmaxf(sqrtf(sq), 1e-12f);
        }
        __syncthreads();
        for (int v = 0; v < NW; ++v) {
            float4 acc = {0.f, 0.f, 0.f, 0.f};
#pragma unroll
            for (int l = 0; l < SEG_L; ++l) {
                ushort4 bb = *(const ushort4*)&qbf[((size_t)(qq * T_LEN + v * 4 + l)) * D_DIM + t * 4];
                acc.x += bf2f(bb.x); acc.y += bf2f(bb.y); acc.z += bf2f(bb.z); acc.w += bf2f(bb.w);
            }
            acc.x *= 0.125f; acc.y *= 0.125f; acc.z *= 0.125f; acc.w *= 0.125f;
            float sq = acc.x * acc.x + acc.y * acc.y + acc.z * acc.z + acc.w * acc.w;
            sq = wsum(sq);
            if (lane == 0) red[v][wv] = sq;
            __syncthreads();
            float tot = red[v][0] + red[v][1] + red[v][2] + red[v][3];
            float scl = 1.0f / fmaxf(sqrtf(tot), 1e-12f);
            float4 o = {acc.x * scl, acc.y * scl, acc.z * scl, acc.w * scl};
            *(ushort4*)&qcondbf[((size_t)(qq * NW + v)) * D_DIM + t * 4] = f2bf4(o);
            __syncthreads();
        }
    } else if (b < Q + C_WAY * K_SHOT) {
        int s = b - Q;
#pragma unroll
        for (int i = 0; i < 16; ++i) {
            int qd = i * 256 + t;
            float4 v = *(const float4*)&sup[(size_t)s * 16384 + qd * 4];
            *(ushort4*)&supbf[(size_t)s * 16384 + qd * 4] = f2bf4(v);
        }
    } else {
        int c = b - Q - C_WAY * K_SHOT;
#pragma unroll
        for (int r0 = 0; r0 < 4; ++r0) {
            int tt = wv * 4 + r0;
            float4 a[4] = {};
            for (int k = 0; k < K_SHOT; ++k)
#pragma unroll
                for (int i = 0; i < 4; ++i) {
                    float4 v = *(const float4*)&sup[((size_t)(c * 80 + k * 16 + tt)) * D_DIM + (i * 64 + lane) * 4];
                    a[i].x += v.x; a[i].y += v.y; a[i].z += v.z; a[i].w += v.w;
                }
            float sq = 0.f;
#pragma unroll
            for (int i = 0; i < 4; ++i) {
                a[i].x *= 0.2f; a[i].y *= 0.2f; a[i].z *= 0.2f; a[i].w *= 0.2f;
                sq += a[i].x * a[i].x + a[i].y * a[i].y + a[i].z * a[i].z + a[i].w * a[i].w;
            }
            sq = wsum(sq);
            if (lane == 0) pn_inv[c * T_LEN + tt] = 1.0f / fmaxf(sqrtf(sq), 1e-12f);
#pragma unroll
            for (int i = 0; i < 4; ++i)
                *(ushort4*)&protobf[((size_t)(c * T_LEN + tt)) * D_DIM + (i * 64 + lane) * 4] = f2bf4(a[i]);
        }
        if (wv < NW) {
            float4 a[4] = {};
            for (int k = 0; k < K_SHOT; ++k)
#pragma unroll
                for (int l = 0; l < SEG_L; ++l)
#pragma unroll
                    for (int i = 0; i < 4; ++i) {
                        float4 v = *(const float4*)&sup[((size_t)(c * 80 + k * 16 + wv * 4 + l)) * D_DIM + (i * 64 + lane) * 4];
                        a[i].x += v.x; a[i].y += v.y; a[i].z += v.z; a[i].w += v.w;
                    }
            float sq = 0.f;
            const float s = 1.0f / 40.0f;
#pragma unroll
            for (int i = 0; i < 4; ++i) {
                a[i].x *= s; a[i].y *= s; a[i].z *= s; a[i].w *= s;
                sq += a[i].x * a[i].x + a[i].y * a[i].y + a[i].z * a[i].z + a[i].w * a[i].w;
            }
            sq = wsum(sq);
            float scl = 1.0f / fmaxf(sqrtf(sq), 1e-12f);
#pragma unroll
            for (int i = 0; i < 4; ++i) {
                float4 o = {a[i].x * scl, a[i].y * scl, a[i].z * scl, a[i].w * scl};
                *(ushort4*)&scondbf[((size_t)(c * NW + wv)) * D_DIM + (i * 64 + lane) * 4] = f2bf4(o);
            }
        }
    }
}

// ================= GEMM tile core: 128x64 block tile, 64x32 per wave =================
// AM/BM: 0=direct, 1=qseg map (A) / cls map (B), 2=cls map with batch
// EPI: true -> SIM path: compute dist=1-dot*qi*pi, per-16x16 min-reduce -> gscore
template <int AM, int BM, bool EPI>
__device__ __forceinline__ void gemm_tile(const unsigned short* __restrict__ A,
                                          const unsigned short* __restrict__ B,
                                          float* __restrict__ Cb,
                                          int M, int N, int m0, int n0, int batch,
                                          unsigned short (&As)[128][72],
                                          unsigned short (&Bs)[64][72],
                                          const float* __restrict__ qrow_inv,
                                          const float* __restrict__ pn_inv,
                                          float* __restrict__ gscore,
                                          float (&qis)[128], float (&pis)[64]) {
    int t = threadIdx.x;
    int arow_l = t >> 1, au = t & 1;   // A: 2 threads/row, 4 uint4 each
    int brow_l = t >> 2, bu = t & 3;   // B: 4 threads/row, 2 uint4 each
    long ga = -1, gb = -1;
    int am = m0 + arow_l;
    if (am < M) ga = (AM == 0) ? am : (AM == 1 ? qseg_row(am) : cls_row(batch * 40 + am));
    int bn = n0 + brow_l;
    if (bn < N) gb = (BM == 0) ? bn : (BM == 1 ? cls_row(bn) : cls_row(batch * 40 + bn));

    int w = t >> 6, l = t & 63;
    int rowbase = (w >> 1) * 64, colbase = (w & 1) * 32;
    int fr = l & 15, fc = l >> 4;

    if (EPI) {
        if (t < 128) qis[t] = qrow_inv[m0 + t];
        else if (t < 192) pis[t - 128] = (n0 + t - 128 < N) ? pn_inv[n0 + t - 128] : 0.f;
    }

    f32x4 acc[4][2] = {};
    uint4 ra[4] = {}, rb[2] = {};
    if (ga >= 0) {
#pragma unroll
        for (int i = 0; i < 4; ++i) ra[i] = *(const uint4*)&A[(size_t)ga * D_DIM + (au + 2 * i) * 8];
    }
    if (gb >= 0) {
#pragma unroll
        for (int i = 0; i < 2; ++i) rb[i] = *(const uint4*)&B[(size_t)gb * D_DIM + (bu + 4 * i) * 8];
    }
    for (int k0 = 0; k0 < D_DIM; k0 += 64) {
        __syncthreads();
#pragma unroll
        for (int i = 0; i < 4; ++i) *(uint4*)&As[arow_l][(au + 2 * i) * 8] = ra[i];
#pragma unroll
        for (int i = 0; i < 2; ++i) *(uint4*)&Bs[brow_l][(bu + 4 * i) * 8] = rb[i];
        __syncthreads();
        int kn = k0 + 64;
        if (kn < D_DIM) {
            if (ga >= 0) {
#pragma unroll
                for (int i = 0; i < 4; ++i) ra[i] = *(const uint4*)&A[(size_t)ga * D_DIM + kn + (au + 2 * i) * 8];
            }
            if (gb >= 0) {
#pragma unroll
                for (int i = 0; i < 2; ++i) rb[i] = *(const uint4*)&B[(size_t)gb * D_DIM + kn + (bu + 4 * i) * 8];
            }
        }
#pragma unroll
        for (int kk = 0; kk < 2; ++kk) {
            bf16x8 b0 = *(const bf16x8*)&Bs[colbase + fr][kk * 32 + fc * 8];
            bf16x8 b1 = *(const bf16x8*)&Bs[colbase + 16 + fr][kk * 32 + fc * 8];
#pragma unroll
            for (int fi = 0; fi < 4; ++fi) {
                bf16x8 a = *(const bf16x8*)&As[rowbase + fi * 16 + fr][kk * 32 + fc * 8];
                acc[fi][0] = __builtin_amdgcn_mfma_f32_16x16x32_bf16(a, b0, acc[fi][0], 0, 0, 0);
                acc[fi][1] = __builtin_amdgcn_mfma_f32_16x16x32_bf16(a, b1, acc[fi][1], 0, 0, 0);
            }
        }
    }
    if (EPI) {
        // per 16x16 (q,c) subtile: row/col min-reduce of dist = 1 - dot*qi*pi
#pragma unroll
        for (int fi = 0; fi < 4; ++fi) {
            float qi[4];
#pragma unroll
            for (int j = 0; j < 4; ++j) qi[j] = qis[rowbase + fi * 16 + fc * 4 + j];
#pragma unroll
            for (int fj = 0; fj < 2; ++fj) {
                int nc = n0 + colbase + fj * 16;
                if (nc >= N) continue;  // wave-uniform
                float pi = pis[colbase + fj * 16 + fr];
                float dd[4], rm[4];
#pragma unroll
                for (int j = 0; j < 4; ++j) { dd[j] = 1.0f - acc[fi][fj][j] * qi[j] * pi; rm[j] = dd[j]; }
#pragma unroll
                for (int o = 1; o <= 8; o <<= 1)
#pragma unroll
                    for (int j = 0; j < 4; ++j) rm[j] = fminf(rm[j], __shfl_xor(rm[j], o));
                float rowsum = rm[0] + rm[1] + rm[2] + rm[3];
                rowsum += __shfl_xor(rowsum, 16);
                rowsum += __shfl_xor(rowsum, 32);
                float cm = fminf(fminf(dd[0], dd[1]), fminf(dd[2], dd[3]));
                cm = fminf(cm, __shfl_xor(cm, 16));
                cm = fminf(cm, __shfl_xor(cm, 32));
                float colsum = cm;
#pragma unroll
                for (int o = 1; o <= 8; o <<= 1) colsum += __shfl_xor(colsum, o);
                if (l == 0) {
                    int qq = (m0 + rowbase) / 16 + fi, cc = nc / 16;
                    gscore[qq * C_WAY + cc] = -(rowsum + colsum);
                }
            }
        }
    } else {
        int crow = fc * 4, ccol = fr;
#pragma unroll
        for (int fi = 0; fi < 4; ++fi)
#pragma unroll
            for (int fj = 0; fj < 2; ++fj)
#pragma unroll
                for (int j = 0; j < 4; ++j) {
                    int m = m0 + rowbase + fi * 16 + crow + j;
                    int n = n0 + colbase + fj * 16 + ccol;
                    if (m < M && n < N) Cb[(size_t)m * N + n] = acc[fi][fj][j];
                }
    }
}

// ================= mega: all GEMMs + Gq in one launch =================
__global__ __launch_bounds__(256) void k_mega(const unsigned short* __restrict__ qbf,
                                              const unsigned short* __restrict__ protobf,
                                              const unsigned short* __restrict__ qcondbf,
                                              const unsigned short* __restrict__ supbf,
                                              const unsigned short* __restrict__ scondbf,
                                              const float* __restrict__ qrow_inv,
                                              const float* __restrict__ pn_inv,
                                              float* __restrict__ gscore,
                                              float* __restrict__ Sraw,
                                              float* __restrict__ Qraw,
                                              float* __restrict__ Gsup,
                                              float* __restrict__ Gq,
                                              int Q, int mt0, int nb0, int mt1, int nb1,
                                              int nb2, int nb3) {
    __shared__ __align__(16) unsigned short As[128][72];
    __shared__ __align__(16) unsigned short Bs[64][72];
    __shared__ float qis[128];
    __shared__ float pis[64];
    int bid = blockIdx.x;
    if (bid < nb0) {  // SIM epilogue-reduced: qbf · protoᵀ [Q*16, 160] -> gscore
        int mtile = bid % mt0, ntile = bid / mt0;
        gemm_tile<0, 0, true>(qbf, protobf, nullptr, Q * T_LEN, 160, mtile * 128, ntile * 64, 0,
                              As, Bs, qrow_inv, pn_inv, gscore, qis, pis);
    } else if (bid < nb0 + nb1) {  // Sraw = qcond · cls_supᵀ [Q*3, 1200]
        int b2 = bid - nb0;
        int mtile = b2 % mt1, ntile = b2 / mt1;
        gemm_tile<0, 1, false>(qcondbf, supbf, Sraw, Q * NW, 1200, mtile * 128, ntile * 64, 0,
                               As, Bs, nullptr, nullptr, nullptr, qis, pis);
    } else if (bid < nb0 + nb1 + nb2) {  // Qraw = q_seg · scondᵀ [Q*24, 30]
        int mtile = bid - nb0 - nb1;
        gemm_tile<1, 0, false>(qbf, scondbf, Qraw, Q * 24, 30, mtile * 128, 0, 0,
                               As, Bs, nullptr, nullptr, nullptr, qis, pis);
    } else if (bid < nb0 + nb1 + nb2 + nb3) {  // Gsup[b] 40x40
        int batch = bid - nb0 - nb1 - nb2;
        gemm_tile<2, 2, false>(supbf, supbf, Gsup + (size_t)batch * 1600, 40, 40, 0, 0, batch,
                               As, Bs, nullptr, nullptr, nullptr, qis, pis);
    } else {  // Gq: each wave does two (q,v) Gram matrices
        int idx = bid - nb0 - nb1 - nb2 - nb3;
        int gw = idx * 4 + (threadIdx.x >> 6);
        int lane = threadIdx.x & 63;
        int QNW = Q * NW;
        int qv0 = gw * 2, qv1 = gw * 2 + 1;
        if (qv0 >= QNW) return;
        int fr = lane & 15, fc = lane >> 4;
        int half = fr >> 3;
        int qv = (half && qv1 < QNW) ? qv1 : qv0;
        int row = (qv / 3) * T_LEN + (qv % 3) * 4 + (fr & 7);
        const unsigned short* src = qbf + (size_t)row * D_DIM + fc * 8;
        f32x4 acc = {};
        for (int k0 = 0; k0 < D_DIM; k0 += 32) {
            bf16x8 f = *(const bf16x8*)&src[k0];
            acc = __builtin_amdgcn_mfma_f32_16x16x32_bf16(f, f, acc, 0, 0, 0);
        }
        if (fr < 8 && fc < 2) {
#pragma unroll
            for (int jj = 0; jj < 4; ++jj)
                Gq[(size_t)qv0 * 64 + (fc * 4 + jj) * 8 + fr] = acc[jj];
        }
        if (fr >= 8 && fc >= 2 && qv1 < QNW) {
#pragma unroll
            for (int jj = 0; jj < 4; ++jj)
                Gq[(size_t)qv1 * 64 + ((fc - 2) * 4 + jj) * 8 + (fr - 8)] = acc[jj];
        }
    }
}

// ================= final: 3 waves per (q,c), wave = w =================
__global__ __launch_bounds__(192) void k_final3(const float* __restrict__ Sraw,
                                                const float* __restrict__ Qraw,
                                                const float* __restrict__ Gsup,
                                                const float* __restrict__ Gq,
                                                const float* __restrict__ gscore,
                                                const float* __restrict__ fusion,
                                                float* __restrict__ out) {
    __shared__ __align__(16) float Gs[3][1600];
    __shared__ float ebuf[3][40];
    __shared__ float e8buf[3][8];
    __shared__ float s2q_all[9], q2s_all[9];
    int bid = blockIdx.x;
    int q = bid / 10, c = bid % 10;
    int w = threadIdx.x >> 6, lane = threadIdx.x & 63;
    const float inv_sqrt_d = 0.03125f;

    const float* Gp = &Gsup[(size_t)(c * 3 + w) * 1600];
#pragma unroll
    for (int j = 0; j < 25; ++j) Gs[w][j * 64 + lane] = Gp[j * 64 + lane];

    for (int v = 0; v < 3; ++v) {
        bool act = lane < 40;
        float raw = act ? Sraw[((size_t)(q * 3 + v)) * 1200 + (c * 3 + w) * 40 + lane] : 0.f;
        float x = act ? raw * inv_sqrt_d : -3.4e38f;
        float mx = wmax(x);
        float e = act ? __expf(x - mx) : 0.f;
        if (act) ebuf[w][lane] = e;
        float dot_e = wsum(e * raw);
        bool a8 = lane < 8;
        float qraw = a8 ? Qraw[((size_t)((q * 3 + v) * 8 + lane)) * 30 + c * 3 + w] : 0.f;
        float x8 = a8 ? qraw * inv_sqrt_d : -3.4e38f;
        float mx8 = wmax8(x8);
        float e8 = a8 ? __expf(x8 - mx8) : 0.f;
        if (a8) e8buf[w][lane] = e8;
        float dot8 = wsum8(e8 * qraw);
        // s2q quadratic form over full 40x40 (25/lane, magic div by 40)
        float acc = 0.f;
#pragma unroll
        for (int j = 0; j < 25; ++j) {
            int i = j * 64 + lane;
            int m = (i * 52429) >> 21;
            int n = i - m * 40;
            acc = fmaf(ebuf[w][m] * ebuf[w][n], Gs[w][i], acc);
        }
        float quad = wsum(acc);
        float sc = dot_e / sqrtf(quad);
        // q2s quadratic form: 1 elem/lane
        int mm = lane >> 3, nn = lane & 7;
        float q2 = e8buf[w][mm] * e8buf[w][nn] * Gq[(size_t)(q * 3 + v) * 64 + lane];
        q2 = wsum(q2);
        float sc8 = __shfl(dot8, 0) / sqrtf(q2);
        if (lane == 0) {
            s2q_all[w * 3 + v] = sc;
            q2s_all[w * 3 + v] = sc8;
        }
    }
    __syncthreads();
    if (threadIdx.x == 0) {
        float b1s = -3.4e38f, b2s = -3.4e38f, b1q = -3.4e38f, b2q = -3.4e38f;
#pragma unroll
        for (int i = 0; i < 9; ++i) {
            float s = s2q_all[i];
            if (s > b1s) { b2s = b1s; b1s = s; } else if (s > b2s) b2s = s;
            float qq2 = q2s_all[i];
            if (qq2 > b1q) { b2q = b1q; b1q = qq2; } else if (qq2 > b2q) b2q = qq2;
        }
        float seg = 0.5f * (0.5f * (b1s + b2s) + 0.5f * (b1q + b2q));
        float l0 = fusion[0], l1 = fusion[1];
        float mmx = fmaxf(l0, l1);
        float e0 = __expf(l0 - mmx), e1 = __expf(l1 - mmx);
        float f0 = e0 / (e0 + e1), f1 = e1 / (e0 + e1);
        out[bid] = f0 * gscore[bid] + f1 * seg;
    }
}

extern "C" void kernel_launch(void* const* d_in, const int* in_sizes, int n_in,
                              void* d_out, int out_size, void* d_ws, size_t ws_size,
                              hipStream_t stream) {
    const float* sup = (const float*)d_in[0];    // [50,16,1024]
    const float* query = (const float*)d_in[1];  // [400,16,1024]
    const float* fusion = (const float*)d_in[2]; // [2]
    float* out = (float*)d_out;                  // [400,10]
    const int Q = in_sizes[1] / (T_LEN * D_DIM); // 400

    float* w = (float*)d_ws;
    size_t off = 0;
    unsigned short* qbf = (unsigned short*)(w + off);     off += (size_t)Q * T_LEN * D_DIM / 2;
    unsigned short* supbf = (unsigned short*)(w + off);   off += (size_t)C_WAY * K_SHOT * T_LEN * D_DIM / 2;
    unsigned short* protobf = (unsigned short*)(w + off); off += (size_t)C_WAY * T_LEN * D_DIM / 2;
    unsigned short* qcondbf = (unsigned short*)(w + off); off += (size_t)Q * NW * D_DIM / 2;
    unsigned short* scondbf = (unsigned short*)(w + off); off += (size_t)C_WAY * NW * D_DIM / 2 + 8;
    float* pn_inv = w + off;    off += C_WAY * T_LEN;
    float* qrow_inv = w + off;  off += (size_t)Q * T_LEN;
    float* gscore = w + off;    off += (size_t)Q * C_WAY;
    float* Gsup = w + off;      off += C_WAY * NW * 40 * 40;
    float* Gq = w + off;        off += (size_t)Q * NW * 64;
    float* Sraw = w + off;      off += (size_t)Q * NW * C_WAY * NW * 40;
    float* Qraw = w + off;      off += (size_t)Q * NW * SEG_L * C_WAY * NW;
    (void)ws_size; (void)n_in; (void)out_size;

    // 1) fused prep
    k_prep<<<Q + C_WAY * K_SHOT + C_WAY, 256, 0, stream>>>(
        sup, query, qbf, qrow_inv, qcondbf, supbf, protobf, pn_inv, scondbf, Q);

    // 2) mega: all GEMMs (128x64 tiles) + Gq
    int mt0 = cdiv(Q * T_LEN, 128), nb0 = mt0 * cdiv(160, 64);
    int mt1 = cdiv(Q * NW, 128), nb1 = mt1 * cdiv(1200, 64);
    int nb2 = cdiv(Q * 24, 128);
    int nb3 = C_WAY * NW;
    int ngq = cdiv(Q * NW, 8);
    k_mega<<<nb0 + nb1 + nb2 + nb3 + ngq, 256, 0, stream>>>(
        qbf, protobf, qcondbf, supbf, scondbf, qrow_inv, pn_inv, gscore,
        Sraw, Qraw, Gsup, Gq, Q, mt0, nb0, mt1, nb1, nb2, nb3);

    // 3) final: 3 waves per (q,c)
    k_final3<<<Q * C_WAY, 192, 0, stream>>>(Sraw, Qraw, Gsup, Gq, gscore, fusion, out);
}

// Round 6
// 73.538 us; speedup vs baseline: 1.5165x; 1.5165x over previous
//
#include <hip/hip_runtime.h>
#include <math.h>

#define C_WAY 10
#define K_SHOT 5
#define T_LEN 16
#define D_DIM 1024
#define NW 3
#define SEG_L 8

typedef __attribute__((ext_vector_type(8))) __bf16 bf16x8;
typedef __attribute__((ext_vector_type(4))) float f32x4;

static inline int cdiv(int a, int b) { return (a + b - 1) / b; }

__device__ __forceinline__ unsigned short f2bf(float f) {
    unsigned int u = __float_as_uint(f);
    u += 0x7fffu + ((u >> 16) & 1u);
    return (unsigned short)(u >> 16);
}
__device__ __forceinline__ float bf2f(unsigned short b) {
    return __uint_as_float(((unsigned int)b) << 16);
}
__device__ __forceinline__ ushort4 f2bf4(float4 v) {
    ushort4 b = {f2bf(v.x), f2bf(v.y), f2bf(v.z), f2bf(v.w)};
    return b;
}

__device__ __forceinline__ float wsum(float v) {
#pragma unroll
    for (int o = 32; o; o >>= 1) v += __shfl_xor(v, o);
    return v;
}
__device__ __forceinline__ float wmax(float v) {
#pragma unroll
    for (int o = 32; o; o >>= 1) v = fmaxf(v, __shfl_xor(v, o));
    return v;
}
__device__ __forceinline__ float wsum8(float v) {
#pragma unroll
    for (int o = 4; o; o >>= 1) v += __shfl_xor(v, o);
    return v;
}
__device__ __forceinline__ float wmax8(float v) {
#pragma unroll
    for (int o = 4; o; o >>= 1) v = fmaxf(v, __shfl_xor(v, o));
    return v;
}

// row-index maps (inline arithmetic)
__device__ __forceinline__ int cls_row(int i) {  // i in [0, 1200)
    int c = i / 120, rem = i - c * 120;
    int w = rem / 40, tok = rem - w * 40;
    return c * 80 + (tok >> 3) * 16 + w * 4 + (tok & 7);
}
__device__ __forceinline__ int qseg_row(int m) {  // m in [0, Q*24)
    int q = m / 24, rem = m - q * 24;
    return q * 16 + (rem >> 3) * 4 + (rem & 7);
}

// ================= fused prep =================
__global__ __launch_bounds__(256) void k_prep(const float* __restrict__ sup,
                                              const float* __restrict__ query,
                                              unsigned short* __restrict__ qbf,
                                              float* __restrict__ qrow_inv,
                                              unsigned short* __restrict__ qcondbf,
                                              unsigned short* __restrict__ supbf,
                                              unsigned short* __restrict__ protobf,
                                              float* __restrict__ pn_inv,
                                              unsigned short* __restrict__ scondbf,
                                              int Q) {
    __shared__ float red[NW][4];
    int b = blockIdx.x;
    int t = threadIdx.x, wv = t >> 6, lane = t & 63;
    if (b < Q) {
        int qq = b;
#pragma unroll
        for (int r0 = 0; r0 < 4; ++r0) {
            int row = qq * T_LEN + wv * 4 + r0;
            float sq = 0.f;
#pragma unroll
            for (int i = 0; i < 4; ++i) {
                float4 v = *(const float4*)&query[(size_t)row * D_DIM + (i * 64 + lane) * 4];
                *(ushort4*)&qbf[(size_t)row * D_DIM + (i * 64 + lane) * 4] = f2bf4(v);
                sq += v.x * v.x + v.y * v.y + v.z * v.z + v.w * v.w;
            }
            sq = wsum(sq);
            if (lane == 0) qrow_inv[row] = 1.0f / fmaxf(sqrtf(sq), 1e-12f);
        }
        __syncthreads();
        for (int v = 0; v < NW; ++v) {
            float4 acc = {0.f, 0.f, 0.f, 0.f};
#pragma unroll
            for (int l = 0; l < SEG_L; ++l) {
                ushort4 bb = *(const ushort4*)&qbf[((size_t)(qq * T_LEN + v * 4 + l)) * D_DIM + t * 4];
                acc.x += bf2f(bb.x); acc.y += bf2f(bb.y); acc.z += bf2f(bb.z); acc.w += bf2f(bb.w);
            }
            acc.x *= 0.125f; acc.y *= 0.125f; acc.z *= 0.125f; acc.w *= 0.125f;
            float sq = acc.x * acc.x + acc.y * acc.y + acc.z * acc.z + acc.w * acc.w;
            sq = wsum(sq);
            if (lane == 0) red[v][wv] = sq;
            __syncthreads();
            float tot = red[v][0] + red[v][1] + red[v][2] + red[v][3];
            float scl = 1.0f / fmaxf(sqrtf(tot), 1e-12f);
            float4 o = {acc.x * scl, acc.y * scl, acc.z * scl, acc.w * scl};
            *(ushort4*)&qcondbf[((size_t)(qq * NW + v)) * D_DIM + t * 4] = f2bf4(o);
            __syncthreads();
        }
    } else if (b < Q + C_WAY * K_SHOT) {
        int s = b - Q;
#pragma unroll
        for (int i = 0; i < 16; ++i) {
            int qd = i * 256 + t;
            float4 v = *(const float4*)&sup[(size_t)s * 16384 + qd * 4];
            *(ushort4*)&supbf[(size_t)s * 16384 + qd * 4] = f2bf4(v);
        }
    } else {
        int c = b - Q - C_WAY * K_SHOT;
#pragma unroll
        for (int r0 = 0; r0 < 4; ++r0) {
            int tt = wv * 4 + r0;
            float4 a[4] = {};
            for (int k = 0; k < K_SHOT; ++k)
#pragma unroll
                for (int i = 0; i < 4; ++i) {
                    float4 v = *(const float4*)&sup[((size_t)(c * 80 + k * 16 + tt)) * D_DIM + (i * 64 + lane) * 4];
                    a[i].x += v.x; a[i].y += v.y; a[i].z += v.z; a[i].w += v.w;
                }
            float sq = 0.f;
#pragma unroll
            for (int i = 0; i < 4; ++i) {
                a[i].x *= 0.2f; a[i].y *= 0.2f; a[i].z *= 0.2f; a[i].w *= 0.2f;
                sq += a[i].x * a[i].x + a[i].y * a[i].y + a[i].z * a[i].z + a[i].w * a[i].w;
            }
            sq = wsum(sq);
            if (lane == 0) pn_inv[c * T_LEN + tt] = 1.0f / fmaxf(sqrtf(sq), 1e-12f);
#pragma unroll
            for (int i = 0; i < 4; ++i)
                *(ushort4*)&protobf[((size_t)(c * T_LEN + tt)) * D_DIM + (i * 64 + lane) * 4] = f2bf4(a[i]);
        }
        if (wv < NW) {
            float4 a[4] = {};
            for (int k = 0; k < K_SHOT; ++k)
#pragma unroll
                for (int l = 0; l < SEG_L; ++l)
#pragma unroll
                    for (int i = 0; i < 4; ++i) {
                        float4 v = *(const float4*)&sup[((size_t)(c * 80 + k * 16 + wv * 4 + l)) * D_DIM + (i * 64 + lane) * 4];
                        a[i].x += v.x; a[i].y += v.y; a[i].z += v.z; a[i].w += v.w;
                    }
            float sq = 0.f;
            const float s = 1.0f / 40.0f;
#pragma unroll
            for (int i = 0; i < 4; ++i) {
                a[i].x *= s; a[i].y *= s; a[i].z *= s; a[i].w *= s;
                sq += a[i].x * a[i].x + a[i].y * a[i].y + a[i].z * a[i].z + a[i].w * a[i].w;
            }
            sq = wsum(sq);
            float scl = 1.0f / fmaxf(sqrtf(sq), 1e-12f);
#pragma unroll
            for (int i = 0; i < 4; ++i) {
                float4 o = {a[i].x * scl, a[i].y * scl, a[i].z * scl, a[i].w * scl};
                *(ushort4*)&scondbf[((size_t)(c * NW + wv)) * D_DIM + (i * 64 + lane) * 4] = f2bf4(o);
            }
        }
    }
}

// ================= GEMM tile core: 64x64 block tile (proven), optional SIM epilogue =================
// AM/BM: 0=direct, 1=qseg map (A) / cls map (B), 2=cls map with batch
// EPI: true -> dist=1-dot*qi*pi, per-16x16 (q,c) subtile min-reduce -> gscore
template <int AM, int BM, bool EPI>
__device__ __forceinline__ void gemm_tile(const unsigned short* __restrict__ A,
                                          const unsigned short* __restrict__ B,
                                          float* __restrict__ Cb,
                                          int M, int N, int m0, int n0, int batch,
                                          unsigned short (&As)[64][72],
                                          unsigned short (&Bs)[64][72],
                                          const float* __restrict__ qrow_inv,
                                          const float* __restrict__ pn_inv,
                                          float* __restrict__ gscore,
                                          float (&qis)[64], float (&pis)[64]) {
    int t = threadIdx.x;
    int srow = t >> 2, sk = (t & 3) * 8;
    long ga = -1, gb = -1;
    int am = m0 + srow;
    if (am < M) ga = (AM == 0) ? am : (AM == 1 ? qseg_row(am) : cls_row(batch * 40 + am));
    int bn = n0 + srow;
    if (bn < N) gb = (BM == 0) ? bn : (BM == 1 ? cls_row(bn) : cls_row(batch * 40 + bn));

    int w = t >> 6, l = t & 63;
    int rowbase = (w >> 1) * 32, colbase = (w & 1) * 32;
    int fr = l & 15, fc = l >> 4;

    if (EPI) {
        if (t < 64) qis[t] = qrow_inv[m0 + t];
        else if (t < 128) pis[t - 64] = (n0 + t - 64 < N) ? pn_inv[n0 + t - 64] : 0.f;
    }

    f32x4 acc[2][2] = {};
    uint4 ra0 = {0, 0, 0, 0}, ra1 = {0, 0, 0, 0}, rb0 = {0, 0, 0, 0}, rb1 = {0, 0, 0, 0};
    if (ga >= 0) {
        ra0 = *(const uint4*)&A[(size_t)ga * D_DIM + sk];
        ra1 = *(const uint4*)&A[(size_t)ga * D_DIM + sk + 32];
    }
    if (gb >= 0) {
        rb0 = *(const uint4*)&B[(size_t)gb * D_DIM + sk];
        rb1 = *(const uint4*)&B[(size_t)gb * D_DIM + sk + 32];
    }
    for (int k0 = 0; k0 < D_DIM; k0 += 64) {
        __syncthreads();
        *(uint4*)&As[srow][sk] = ra0;
        *(uint4*)&As[srow][sk + 32] = ra1;
        *(uint4*)&Bs[srow][sk] = rb0;
        *(uint4*)&Bs[srow][sk + 32] = rb1;
        __syncthreads();
        int kn = k0 + 64;
        if (kn < D_DIM) {
            if (ga >= 0) {
                ra0 = *(const uint4*)&A[(size_t)ga * D_DIM + kn + sk];
                ra1 = *(const uint4*)&A[(size_t)ga * D_DIM + kn + sk + 32];
            }
            if (gb >= 0) {
                rb0 = *(const uint4*)&B[(size_t)gb * D_DIM + kn + sk];
                rb1 = *(const uint4*)&B[(size_t)gb * D_DIM + kn + sk + 32];
            }
        }
#pragma unroll
        for (int kk = 0; kk < 2; ++kk) {
            bf16x8 a0 = *(const bf16x8*)&As[rowbase + fr][kk * 32 + fc * 8];
            bf16x8 a1 = *(const bf16x8*)&As[rowbase + 16 + fr][kk * 32 + fc * 8];
            bf16x8 b0 = *(const bf16x8*)&Bs[colbase + fr][kk * 32 + fc * 8];
            bf16x8 b1 = *(const bf16x8*)&Bs[colbase + 16 + fr][kk * 32 + fc * 8];
            acc[0][0] = __builtin_amdgcn_mfma_f32_16x16x32_bf16(a0, b0, acc[0][0], 0, 0, 0);
            acc[0][1] = __builtin_amdgcn_mfma_f32_16x16x32_bf16(a0, b1, acc[0][1], 0, 0, 0);
            acc[1][0] = __builtin_amdgcn_mfma_f32_16x16x32_bf16(a1, b0, acc[1][0], 0, 0, 0);
            acc[1][1] = __builtin_amdgcn_mfma_f32_16x16x32_bf16(a1, b1, acc[1][1], 0, 0, 0);
        }
    }
    if (EPI) {
        // each (fi,fj) fragment is one 16x16 (q,c) subtile
#pragma unroll
        for (int fi = 0; fi < 2; ++fi) {
            float qi[4];
#pragma unroll
            for (int j = 0; j < 4; ++j) qi[j] = qis[rowbase + fi * 16 + fc * 4 + j];
#pragma unroll
            for (int fj = 0; fj < 2; ++fj) {
                int nc = n0 + colbase + fj * 16;
                if (nc >= N) continue;  // wave-uniform
                float pi = pis[colbase + fj * 16 + fr];
                float dd[4], rm[4];
#pragma unroll
                for (int j = 0; j < 4; ++j) { dd[j] = 1.0f - acc[fi][fj][j] * qi[j] * pi; rm[j] = dd[j]; }
#pragma unroll
                for (int o = 1; o <= 8; o <<= 1)
#pragma unroll
                    for (int j = 0; j < 4; ++j) rm[j] = fminf(rm[j], __shfl_xor(rm[j], o));
                float rowsum = rm[0] + rm[1] + rm[2] + rm[3];
                rowsum += __shfl_xor(rowsum, 16);
                rowsum += __shfl_xor(rowsum, 32);
                float cm = fminf(fminf(dd[0], dd[1]), fminf(dd[2], dd[3]));
                cm = fminf(cm, __shfl_xor(cm, 16));
                cm = fminf(cm, __shfl_xor(cm, 32));
                float colsum = cm;
#pragma unroll
                for (int o = 1; o <= 8; o <<= 1) colsum += __shfl_xor(colsum, o);
                if (l == 0) {
                    int qq = (m0 + rowbase) / 16 + fi, cc = nc / 16;
                    gscore[qq * C_WAY + cc] = -(rowsum + colsum);
                }
            }
        }
    } else {
        int crow = fc * 4, ccol = fr;
#pragma unroll
        for (int fi = 0; fi < 2; ++fi)
#pragma unroll
            for (int fj = 0; fj < 2; ++fj)
#pragma unroll
                for (int j = 0; j < 4; ++j) {
                    int m = m0 + rowbase + fi * 16 + crow + j;
                    int n = n0 + colbase + fj * 16 + ccol;
                    if (m < M && n < N) Cb[(size_t)m * N + n] = acc[fi][fj][j];
                }
    }
}

// ================= mega: all GEMMs + Gq in one launch =================
__global__ __launch_bounds__(256) void k_mega(const unsigned short* __restrict__ qbf,
                                              const unsigned short* __restrict__ protobf,
                                              const unsigned short* __restrict__ qcondbf,
                                              const unsigned short* __restrict__ supbf,
                                              const unsigned short* __restrict__ scondbf,
                                              const float* __restrict__ qrow_inv,
                                              const float* __restrict__ pn_inv,
                                              float* __restrict__ gscore,
                                              float* __restrict__ Sraw,
                                              float* __restrict__ Qraw,
                                              float* __restrict__ Gsup,
                                              float* __restrict__ Gq,
                                              int Q, int mt0, int nb0, int mt1, int nb1,
                                              int nb2, int nb3) {
    __shared__ __align__(16) unsigned short As[64][72];
    __shared__ __align__(16) unsigned short Bs[64][72];
    __shared__ float qis[64];
    __shared__ float pis[64];
    int bid = blockIdx.x;
    if (bid < nb0) {  // SIM fused: qbf · protoᵀ [Q*16, 160] -> gscore directly
        int mtile = bid % mt0, ntile = bid / mt0;
        gemm_tile<0, 0, true>(qbf, protobf, nullptr, Q * T_LEN, 160, mtile * 64, ntile * 64, 0,
                              As, Bs, qrow_inv, pn_inv, gscore, qis, pis);
    } else if (bid < nb0 + nb1) {  // Sraw = qcond · cls_supᵀ [Q*3, 1200]
        int b2 = bid - nb0;
        int mtile = b2 % mt1, ntile = b2 / mt1;
        gemm_tile<0, 1, false>(qcondbf, supbf, Sraw, Q * NW, 1200, mtile * 64, ntile * 64, 0,
                               As, Bs, nullptr, nullptr, nullptr, qis, pis);
    } else if (bid < nb0 + nb1 + nb2) {  // Qraw = q_seg · scondᵀ [Q*24, 30]
        int mtile = bid - nb0 - nb1;
        gemm_tile<1, 0, false>(qbf, scondbf, Qraw, Q * 24, 30, mtile * 64, 0, 0,
                               As, Bs, nullptr, nullptr, nullptr, qis, pis);
    } else if (bid < nb0 + nb1 + nb2 + nb3) {  // Gsup[b] 40x40
        int batch = bid - nb0 - nb1 - nb2;
        gemm_tile<2, 2, false>(supbf, supbf, Gsup + (size_t)batch * 1600, 40, 40, 0, 0, batch,
                               As, Bs, nullptr, nullptr, nullptr, qis, pis);
    } else {  // Gq: each wave does two (q,v) Gram matrices
        int idx = bid - nb0 - nb1 - nb2 - nb3;
        int gw = idx * 4 + (threadIdx.x >> 6);
        int lane = threadIdx.x & 63;
        int QNW = Q * NW;
        int qv0 = gw * 2, qv1 = gw * 2 + 1;
        if (qv0 >= QNW) return;
        int fr = lane & 15, fc = lane >> 4;
        int half = fr >> 3;
        int qv = (half && qv1 < QNW) ? qv1 : qv0;
        int row = (qv / 3) * T_LEN + (qv % 3) * 4 + (fr & 7);
        const unsigned short* src = qbf + (size_t)row * D_DIM + fc * 8;
        f32x4 acc = {};
        for (int k0 = 0; k0 < D_DIM; k0 += 32) {
            bf16x8 f = *(const bf16x8*)&src[k0];
            acc = __builtin_amdgcn_mfma_f32_16x16x32_bf16(f, f, acc, 0, 0, 0);
        }
        if (fr < 8 && fc < 2) {
#pragma unroll
            for (int jj = 0; jj < 4; ++jj)
                Gq[(size_t)qv0 * 64 + (fc * 4 + jj) * 8 + fr] = acc[jj];
        }
        if (fr >= 8 && fc >= 2 && qv1 < QNW) {
#pragma unroll
            for (int jj = 0; jj < 4; ++jj)
                Gq[(size_t)qv1 * 64 + ((fc - 2) * 4 + jj) * 8 + (fr - 8)] = acc[jj];
        }
    }
}

// ================= final: 3 waves per (q,c), wave = w =================
__global__ __launch_bounds__(192) void k_final3(const float* __restrict__ Sraw,
                                                const float* __restrict__ Qraw,
                                                const float* __restrict__ Gsup,
                                                const float* __restrict__ Gq,
                                                const float* __restrict__ gscore,
                                                const float* __restrict__ fusion,
                                                float* __restrict__ out) {
    __shared__ __align__(16) float Gs[3][1600];
    __shared__ float ebuf[3][40];
    __shared__ float e8buf[3][8];
    __shared__ float s2q_all[9], q2s_all[9];
    int bid = blockIdx.x;
    int q = bid / 10, c = bid % 10;
    int w = threadIdx.x >> 6, lane = threadIdx.x & 63;
    const float inv_sqrt_d = 0.03125f;

    const float* Gp = &Gsup[(size_t)(c * 3 + w) * 1600];
#pragma unroll
    for (int j = 0; j < 25; ++j) Gs[w][j * 64 + lane] = Gp[j * 64 + lane];

    for (int v = 0; v < 3; ++v) {
        bool act = lane < 40;
        float raw = act ? Sraw[((size_t)(q * 3 + v)) * 1200 + (c * 3 + w) * 40 + lane] : 0.f;
        float x = act ? raw * inv_sqrt_d : -3.4e38f;
        float mx = wmax(x);
        float e = act ? __expf(x - mx) : 0.f;
        if (act) ebuf[w][lane] = e;
        float dot_e = wsum(e * raw);
        bool a8 = lane < 8;
        float qraw = a8 ? Qraw[((size_t)((q * 3 + v) * 8 + lane)) * 30 + c * 3 + w] : 0.f;
        float x8 = a8 ? qraw * inv_sqrt_d : -3.4e38f;
        float mx8 = wmax8(x8);
        float e8 = a8 ? __expf(x8 - mx8) : 0.f;
        if (a8) e8buf[w][lane] = e8;
        float dot8 = wsum8(e8 * qraw);
        // s2q quadratic form over full 40x40 (25/lane, magic div by 40)
        float acc = 0.f;
#pragma unroll
        for (int j = 0; j < 25; ++j) {
            int i = j * 64 + lane;
            int m = (i * 52429) >> 21;
            int n = i - m * 40;
            acc = fmaf(ebuf[w][m] * ebuf[w][n], Gs[w][i], acc);
        }
        float quad = wsum(acc);
        float sc = dot_e / sqrtf(quad);
        // q2s quadratic form: 1 elem/lane
        int mm = lane >> 3, nn = lane & 7;
        float q2 = e8buf[w][mm] * e8buf[w][nn] * Gq[(size_t)(q * 3 + v) * 64 + lane];
        q2 = wsum(q2);
        float sc8 = __shfl(dot8, 0) / sqrtf(q2);
        if (lane == 0) {
            s2q_all[w * 3 + v] = sc;
            q2s_all[w * 3 + v] = sc8;
        }
    }
    __syncthreads();
    if (threadIdx.x == 0) {
        float b1s = -3.4e38f, b2s = -3.4e38f, b1q = -3.4e38f, b2q = -3.4e38f;
#pragma unroll
        for (int i = 0; i < 9; ++i) {
            float s = s2q_all[i];
            if (s > b1s) { b2s = b1s; b1s = s; } else if (s > b2s) b2s = s;
            float qq2 = q2s_all[i];
            if (qq2 > b1q) { b2q = b1q; b1q = qq2; } else if (qq2 > b2q) b2q = qq2;
        }
        float seg = 0.5f * (0.5f * (b1s + b2s) + 0.5f * (b1q + b2q));
        float l0 = fusion[0], l1 = fusion[1];
        float mmx = fmaxf(l0, l1);
        float e0 = __expf(l0 - mmx), e1 = __expf(l1 - mmx);
        float f0 = e0 / (e0 + e1), f1 = e1 / (e0 + e1);
        out[bid] = f0 * gscore[bid] + f1 * seg;
    }
}

extern "C" void kernel_launch(void* const* d_in, const int* in_sizes, int n_in,
                              void* d_out, int out_size, void* d_ws, size_t ws_size,
                              hipStream_t stream) {
    const float* sup = (const float*)d_in[0];    // [50,16,1024]
    const float* query = (const float*)d_in[1];  // [400,16,1024]
    const float* fusion = (const float*)d_in[2]; // [2]
    float* out = (float*)d_out;                  // [400,10]
    const int Q = in_sizes[1] / (T_LEN * D_DIM); // 400

    float* w = (float*)d_ws;
    size_t off = 0;
    unsigned short* qbf = (unsigned short*)(w + off);     off += (size_t)Q * T_LEN * D_DIM / 2;
    unsigned short* supbf = (unsigned short*)(w + off);   off += (size_t)C_WAY * K_SHOT * T_LEN * D_DIM / 2;
    unsigned short* protobf = (unsigned short*)(w + off); off += (size_t)C_WAY * T_LEN * D_DIM / 2;
    unsigned short* qcondbf = (unsigned short*)(w + off); off += (size_t)Q * NW * D_DIM / 2;
    unsigned short* scondbf = (unsigned short*)(w + off); off += (size_t)C_WAY * NW * D_DIM / 2 + 8;
    float* pn_inv = w + off;    off += C_WAY * T_LEN;
    float* qrow_inv = w + off;  off += (size_t)Q * T_LEN;
    float* gscore = w + off;    off += (size_t)Q * C_WAY;
    float* Gsup = w + off;      off += C_WAY * NW * 40 * 40;
    float* Gq = w + off;        off += (size_t)Q * NW * 64;
    float* Sraw = w + off;      off += (size_t)Q * NW * C_WAY * NW * 40;
    float* Qraw = w + off;      off += (size_t)Q * NW * SEG_L * C_WAY * NW;
    (void)ws_size; (void)n_in; (void)out_size;

    // 1) fused prep
    k_prep<<<Q + C_WAY * K_SHOT + C_WAY, 256, 0, stream>>>(
        sup, query, qbf, qrow_inv, qcondbf, supbf, protobf, pn_inv, scondbf, Q);

    // 2) mega: all GEMMs (64x64 tiles, 991 blocks) + Gq
    int mt0 = cdiv(Q * T_LEN, 64), nb0 = mt0 * cdiv(160, 64);
    int mt1 = cdiv(Q * NW, 64), nb1 = mt1 * cdiv(1200, 64);
    int nb2 = cdiv(Q * 24, 64);
    int nb3 = C_WAY * NW;
    int ngq = cdiv(Q * NW, 8);
    k_mega<<<nb0 + nb1 + nb2 + nb3 + ngq, 256, 0, stream>>>(
        qbf, protobf, qcondbf, supbf, scondbf, qrow_inv, pn_inv, gscore,
        Sraw, Qraw, Gsup, Gq, Q, mt0, nb0, mt1, nb1, nb2, nb3);

    // 3) final: 3 waves per (q,c)
    k_final3<<<Q * C_WAY, 192, 0, stream>>>(Sraw, Qraw, Gsup, Gq, gscore, fusion, out);
}